// Round 6
// baseline (329.193 us; speedup 1.0000x reference)
//
#include <hip/hip_runtime.h>

#define NNODES 50000
#define NEDGES 200000
#define DD 128
#define LN_EPS 1e-5f
#define NTH 256

typedef __attribute__((ext_vector_type(8))) short bf16x8;
typedef __attribute__((ext_vector_type(4))) float f32x4;
typedef __attribute__((ext_vector_type(16))) float f32x16;

template<int N> struct ic { static constexpr int value = N; };

__device__ __forceinline__ unsigned short bf_rne(float f) {
    union { float f; unsigned u; } v; v.f = f;
    return (unsigned short)((v.u + 0x7fffu + ((v.u >> 16) & 1u)) >> 16);
}

__device__ __forceinline__ void gload_lds16(const void* g, void* l) {
    __builtin_amdgcn_global_load_lds(
        (const __attribute__((address_space(1))) void*)g,
        (__attribute__((address_space(3))) void*)l, 16, 0, 0);
}

// ---------------------------------------------------------------------------
// Weight image for 32x32x16 MFMA. Per k32 chunk c (8 KB):
//   granule(ntile, n32, ks): byte = c*8192 + ntile*2048 + n32*64
//                                   + ((ks ^ ((n32 + (n32>>2)) & 3)) << 4)
//   content: Wt[n = ntile*32+n32][k = c*32 + ks*8 + e], e=0..7 (bf16)
// Swizzle gives distinct bank-groups per 8-lane phase on ds_read_b128.
// global_load_lds copies linearly -> LDS layout == image layout (rule 21).
// ---------------------------------------------------------------------------
__global__ void build_wimg(const float* __restrict__ We1, const float* __restrict__ We2,
                           const float* __restrict__ We3, const float* __restrict__ Wn1,
                           const float* __restrict__ Wn2, const float* __restrict__ Wn3,
                           char* __restrict__ img_e, char* __restrict__ img_n) {
    int tid = blockIdx.x * NTH + threadIdx.x;
    const float* W; char* dst; int q;
    if      (tid <  6144) { W = We1; dst = img_e;             q = tid;         }
    else if (tid <  8192) { W = We2; dst = img_e + 12 * 8192; q = tid - 6144;  }
    else if (tid < 10240) { W = We3; dst = img_e + 16 * 8192; q = tid - 8192;  }
    else if (tid < 14336) { W = Wn1; dst = img_n;             q = tid - 10240; }
    else if (tid < 16384) { W = Wn2; dst = img_n + 8 * 8192;  q = tid - 14336; }
    else if (tid < 18432) { W = Wn3; dst = img_n + 12 * 8192; q = tid - 16384; }
    else return;
    int c = q >> 9, rem = q & 511;
    int ntile = rem >> 7, r2 = rem & 127, n32 = r2 >> 2, ks = r2 & 3;
    int n = ntile * 32 + n32;
    int sx = (n32 + (n32 >> 2)) & 3;
    int k0 = c * 32 + ks * 8;
    unsigned short o[8];
    #pragma unroll
    for (int e = 0; e < 8; ++e)
        o[e] = bf_rne(W[(size_t)(k0 + e) * DD + n]);
    uint4 val;
    val.x = (unsigned)o[0] | ((unsigned)o[1] << 16);
    val.y = (unsigned)o[2] | ((unsigned)o[3] << 16);
    val.z = (unsigned)o[4] | ((unsigned)o[5] << 16);
    val.w = (unsigned)o[6] | ((unsigned)o[7] << 16);
    *(uint4*)(dst + (size_t)c * 8192 + ntile * 2048 + n32 * 64 + ((ks ^ sx) << 4)) = val;
}

// ---------------------------------------------------------------------------
// CSR build: histogram -> single-block scan -> fill
// ---------------------------------------------------------------------------
__global__ void csr_histo(const int* __restrict__ recv, int* __restrict__ cnt) {
    int e = blockIdx.x * NTH + threadIdx.x;
    if (e < NEDGES) atomicAdd(&cnt[recv[e]], 1);
}

__global__ __launch_bounds__(1024)
void csr_scan(const int* __restrict__ cnt, int* __restrict__ off, int* __restrict__ cursor) {
    __shared__ int part[1024];
    const int t = threadIdx.x;
    const int CH = (NNODES + 1023) / 1024;
    const int base = t * CH;
    int s = 0;
    for (int i = 0; i < CH; ++i) {
        int idx = base + i;
        if (idx < NNODES) s += cnt[idx];
    }
    part[t] = s;
    __syncthreads();
    for (int d = 1; d < 1024; d <<= 1) {
        int v = (t >= d) ? part[t - d] : 0;
        __syncthreads();
        part[t] += v;
        __syncthreads();
    }
    int run = (t == 0) ? 0 : part[t - 1];
    for (int i = 0; i < CH; ++i) {
        int idx = base + i;
        if (idx < NNODES) {
            off[idx] = run; cursor[idx] = run;
            run += cnt[idx];
        }
    }
    if (t == 1023) off[NNODES] = NEDGES;
}

__global__ void csr_fill(const int* __restrict__ recv, int* __restrict__ cursor,
                         int* __restrict__ elist) {
    int e = blockIdx.x * NTH + threadIdx.x;
    if (e < NEDGES) {
        int p = atomicAdd(&cursor[recv[e]], 1);
        elist[p] = e;
    }
}

// ---------------------------------------------------------------------------
// Aggregate: agg[n] = sum over receiver-edges of (out_edge[e] - edgef[e])
// ---------------------------------------------------------------------------
__global__ __launch_bounds__(NTH)
void aggregate(const float* __restrict__ oute, const float* __restrict__ edgef,
               const int* __restrict__ off, const int* __restrict__ elist,
               float* __restrict__ agg) {
    const int n = blockIdx.x * 4 + (threadIdx.x >> 6);
    const int l = threadIdx.x & 63;
    if (n >= NNODES) return;
    const int j0 = off[n], j1 = off[n + 1];
    float ax = 0.f, ay = 0.f, bx = 0.f, by = 0.f;
    int j = j0;
    for (; j + 1 < j1; j += 2) {
        const int e0 = elist[j], e1 = elist[j + 1];
        const float2 o0 = ((const float2*)(oute  + (size_t)e0 * DD))[l];
        const float2 f0 = ((const float2*)(edgef + (size_t)e0 * DD))[l];
        const float2 o1 = ((const float2*)(oute  + (size_t)e1 * DD))[l];
        const float2 f1 = ((const float2*)(edgef + (size_t)e1 * DD))[l];
        ax += o0.x - f0.x; ay += o0.y - f0.y;
        bx += o1.x - f1.x; by += o1.y - f1.y;
    }
    if (j < j1) {
        const int e = elist[j];
        const float2 o  = ((const float2*)(oute  + (size_t)e * DD))[l];
        const float2 ef = ((const float2*)(edgef + (size_t)e * DD))[l];
        ax += o.x - ef.x; ay += o.y - ef.y;
    }
    float2 r; r.x = ax + bx; r.y = ay + by;
    ((float2*)(agg + (size_t)n * DD))[l] = r;
}

// ---------------------------------------------------------------------------
// Fused MLP, 32x32x16 MFMA.  MODE 0 = edge (K=384), MODE 1 = node (K=256).
// 4 waves x 32 rows = 128 rows/block; each wave computes all 128 cols.
// C layout (m74/m101): col(=X row m) = l&31, row(=W col n) =
//   (reg&3) + 8*(reg>>2) + 4*(l>>5), per 32-col ntile.
// Weights: 8 KB k32 chunks via global_load_lds, 5 LDS buffers, stage depth 3,
// counted vmcnt (issue schedule pinned by sched_barrier), 1 s_barrier/chunk.
// B: per-lane row gathers (32 rows/wave), reg rotation depth 3.
// H1/H2: wave-private 32x128 bf16 LDS, slot-XOR swizzled, no barriers.
// ---------------------------------------------------------------------------
template<int MODE>
__global__ __launch_bounds__(NTH, 2)
void mgn_mfma(const float* __restrict__ nodef, const float* __restrict__ edgef,
              const int* __restrict__ senders, const int* __restrict__ receivers,
              const char* __restrict__ img,
              const float* __restrict__ b1, const float* __restrict__ b2,
              const float* __restrict__ b3,
              const float* __restrict__ gamma, const float* __restrict__ beta,
              const float* __restrict__ agg, float* __restrict__ outp)
{
    __shared__ char Wbuf[5 * 8192];   // 5 rotating k32 weight chunks
    __shared__ char Hb[4 * 8192];     // per-wave 32 rows x 128 k bf16, swizzled

    const int t  = threadIdx.x;
    const int w  = t >> 6;
    const int l  = t & 63;
    const int ln = l & 31;            // A: weight row n32 | B/C: X row m32
    const int hi = l >> 5;
    const int row0 = blockIdx.x * 128;
    const int gm = row0 + w * 32 + ln;
    constexpr int NROWS = (MODE == 0) ? NEDGES : NNODES;
    constexpr int NK1   = (MODE == 0) ? 12 : 8;
    constexpr int NCH   = NK1 + 8;
    const int gmc = gm < NROWS ? gm : NROWS - 1;
    const int sxA = (ln + (ln >> 2)) & 3;     // A slot swizzle
    const int sxH = ln & 15;                  // Hb slot swizzle

    int srow = 0, rrow = 0;
    if (MODE == 0) { srow = senders[gmc]; rrow = receivers[gmc]; }

    const f32x16 fz = {0.f,0.f,0.f,0.f,0.f,0.f,0.f,0.f,
                       0.f,0.f,0.f,0.f,0.f,0.f,0.f,0.f};
    f32x16 acc[4];
    #pragma unroll
    for (int nt = 0; nt < 4; ++nt) acc[nt] = fz;

    f32x4 barr[3][4];

    // ---- stage weight chunk c into Wbuf[c%5] ----
    auto stageW = [&](int c) {
        const char* src = img + (size_t)c * 8192 + t * 16;
        char* dstl = Wbuf + (c % 5) * 8192 + t * 16;
        gload_lds16(src, dstl);
        gload_lds16(src + 4096, dstl + 4096);
    };

    // ---- B gather for chunk c: lane covers its row's floats
    //      [c*32 + hi*8 .. +7] and [c*32 + 16 + hi*8 .. +7] ----
    auto loadBG = [&](int c, f32x4* dst) {
        const float* base;
        if (MODE == 0) {
            base = (c < 4) ? nodef + (size_t)srow * DD
                 : (c < 8) ? nodef + (size_t)rrow * DD
                           : edgef + (size_t)gmc * DD;
        } else {
            base = (c < 4) ? nodef + (size_t)gmc * DD
                           : agg   + (size_t)gmc * DD;
        }
        const float* p = base + (c & 3) * 32 + hi * 8;
        dst[0] = *(const f32x4*)p;
        dst[1] = *(const f32x4*)(p + 4);
        dst[2] = *(const f32x4*)(p + 16);
        dst[3] = *(const f32x4*)(p + 20);
    };

    auto cvtB = [&](const f32x4* br) {
        bf16x8 r;
        #pragma unroll
        for (int i = 0; i < 4; ++i) r[i]     = (short)bf_rne(br[0][i]);
        #pragma unroll
        for (int i = 0; i < 4; ++i) r[4 + i] = (short)bf_rne(br[1][i]);
        return r;
    };

    // ---- H read: 16 B slot sk = ks*4 + kh*2 + hi, swizzled ----
    auto loadBH = [&](int ks, int kh) {
        const char* p = Hb + w * 8192 + ln * 256
                      + (((ks * 4 + kh * 2 + hi) ^ sxH) << 4);
        return *(const bf16x8*)p;
    };

    // ---- bias + relu -> Hb (quad writes, 8 B), reset acc ----
    auto epiH = [&](const float* bias) {
        #pragma unroll
        for (int nt = 0; nt < 4; ++nt) {
            #pragma unroll
            for (int rq = 0; rq < 4; ++rq) {
                f32x4 bv = *(const f32x4*)(bias + nt * 32 + rq * 8 + hi * 4);
                unsigned short h[4];
                #pragma unroll
                for (int j = 0; j < 4; ++j)
                    h[j] = bf_rne(fmaxf(acc[nt][rq * 4 + j] + bv[j], 0.f));
                char* p = Hb + w * 8192 + ln * 256
                        + (((nt * 4 + rq) ^ sxH) << 4) + hi * 8;
                unsigned lo = (unsigned)h[0] | ((unsigned)h[1] << 16);
                unsigned hx = (unsigned)h[2] | ((unsigned)h[3] << 16);
                *(unsigned long long*)p =
                    (unsigned long long)lo | ((unsigned long long)hx << 32);
            }
            acc[nt] = fz;
        }
    };

    // ---- compute chunk c ----
    auto compute = [&](auto cc) {
        constexpr int c = decltype(cc)::value;
        const char* bp = Wbuf + (c % 5) * 8192 + ln * 64;
        #pragma unroll
        for (int kh = 0; kh < 2; ++kh) {
            bf16x8 b;
            if constexpr (c < NK1) b = cvtB(&barr[c % 3][kh * 2]);
            else                   b = loadBH((c - NK1) & 3, kh);
            #pragma unroll
            for (int nt = 0; nt < 4; ++nt) {
                bf16x8 a = *(const bf16x8*)(bp + nt * 2048
                            + (((kh * 2 + hi) ^ sxA) << 4));
                acc[nt] = __builtin_amdgcn_mfma_f32_32x32x16_bf16(a, b, acc[nt], 0, 0, 0);
            }
        }
    };

#define PITER(C, VM)                                                        \
    {                                                                       \
        if constexpr ((C) + 3 < NCH) stageW((C) + 3);                       \
        __builtin_amdgcn_sched_barrier(0);                                  \
        if constexpr ((C) + 2 < NK1) loadBG((C) + 2, barr[((C) + 2) % 3]);  \
        __builtin_amdgcn_sched_barrier(0);                                  \
        asm volatile("s_waitcnt vmcnt(" #VM ")" ::: "memory");              \
        __builtin_amdgcn_sched_barrier(0);                                  \
        __builtin_amdgcn_s_barrier();                                       \
        __builtin_amdgcn_sched_barrier(0);                                  \
        compute(ic<(C)>{});                                                 \
    }

    // prologue: stages 0..2, B 0..1 (order pinned)
    stageW(0);
    __builtin_amdgcn_sched_barrier(0);
    loadBG(0, barr[0]);
    __builtin_amdgcn_sched_barrier(0);
    stageW(1);
    __builtin_amdgcn_sched_barrier(0);
    loadBG(1, barr[1]);
    __builtin_amdgcn_sched_barrier(0);
    stageW(2);
    __builtin_amdgcn_sched_barrier(0);

    if constexpr (MODE == 0) {
        PITER(0, 18)  PITER(1, 18)  PITER(2, 18)  PITER(3, 22)  PITER(4, 22)
        PITER(5, 22)  PITER(6, 22)  PITER(7, 22)  PITER(8, 22)  PITER(9, 22)
        PITER(10, 18) PITER(11, 14)
        epiH(b1);
        PITER(12, 10) PITER(13, 6)  PITER(14, 6)  PITER(15, 6)
        epiH(b2);
        PITER(16, 6)  PITER(17, 4)  PITER(18, 2)  PITER(19, 0)
    } else {
        PITER(0, 18)  PITER(1, 18)  PITER(2, 18)  PITER(3, 22)  PITER(4, 22)
        PITER(5, 22)  PITER(6, 18)  PITER(7, 14)
        epiH(b1);
        PITER(8, 10)  PITER(9, 6)   PITER(10, 6)  PITER(11, 6)
        epiH(b2);
        PITER(12, 6)  PITER(13, 4)  PITER(14, 2)  PITER(15, 0)
    }
#undef PITER

    // ================= bias3 + LayerNorm + residual =================
    float vsum = 0.f, vsq = 0.f;
    #pragma unroll
    for (int nt = 0; nt < 4; ++nt) {
        #pragma unroll
        for (int rq = 0; rq < 4; ++rq) {
            f32x4 bv = *(const f32x4*)(b3 + nt * 32 + rq * 8 + hi * 4);
            #pragma unroll
            for (int j = 0; j < 4; ++j) {
                float v = acc[nt][rq * 4 + j] + bv[j];
                acc[nt][rq * 4 + j] = v;
                vsum += v; vsq += v * v;
            }
        }
    }
    vsum += __shfl_xor(vsum, 32);
    vsq  += __shfl_xor(vsq, 32);
    const float mu = vsum * (1.f / DD);
    const float rs = rsqrtf(vsq * (1.f / DD) - mu * mu + LN_EPS);

    if (gm < NROWS) {
        const float* resid = ((MODE == 0) ? edgef : nodef) + (size_t)gm * DD;
        #pragma unroll
        for (int nt = 0; nt < 4; ++nt) {
            #pragma unroll
            for (int rq = 0; rq < 4; ++rq) {
                const int n0 = nt * 32 + rq * 8 + hi * 4;
                f32x4 gv = *(const f32x4*)(gamma + n0);
                f32x4 bv = *(const f32x4*)(beta + n0);
                f32x4 rv = *(const f32x4*)(resid + n0);
                f32x4 o;
                #pragma unroll
                for (int j = 0; j < 4; ++j)
                    o[j] = (acc[nt][rq * 4 + j] - mu) * rs * gv[j] + bv[j] + rv[j];
                *(f32x4*)(outp + (size_t)gm * DD + n0) = o;
            }
        }
    }
}

extern "C" void kernel_launch(void* const* d_in, const int* in_sizes, int n_in,
                              void* d_out, int out_size, void* d_ws, size_t ws_size,
                              hipStream_t stream) {
    const float* nodef = (const float*)d_in[0];
    const float* edgef = (const float*)d_in[1];
    const int* senders   = (const int*)d_in[2];
    const int* receivers = (const int*)d_in[3];
    const float* We1 = (const float*)d_in[4],  *be1 = (const float*)d_in[5];
    const float* We2 = (const float*)d_in[6],  *be2 = (const float*)d_in[7];
    const float* We3 = (const float*)d_in[8],  *be3 = (const float*)d_in[9];
    const float* ge  = (const float*)d_in[10], *bege = (const float*)d_in[11];
    const float* Wn1 = (const float*)d_in[12], *bn1 = (const float*)d_in[13];
    const float* Wn2 = (const float*)d_in[14], *bn2 = (const float*)d_in[15];
    const float* Wn3 = (const float*)d_in[16], *bn3 = (const float*)d_in[17];
    const float* gn  = (const float*)d_in[18], *begn = (const float*)d_in[19];

    float* out_node = (float*)d_out;
    float* out_edge = (float*)d_out + (size_t)NNODES * DD;

    char* ws = (char*)d_ws;
    size_t o = 0;
    float* agg  = (float*)(ws + o); o += (size_t)NNODES * DD * 4;   // 25.6 MB
    char* img_e = ws + o;           o += 20 * 8192;                  // 160 KB
    char* img_n = ws + o;           o += 16 * 8192;                  // 128 KB
    int* cnt    = (int*)(ws + o);   o += NNODES * 4;
    int* cursor = (int*)(ws + o);   o += NNODES * 4;
    int* off    = (int*)(ws + o);   o += (NNODES + 4) * 4;
    int* elist  = (int*)(ws + o);   o += NEDGES * 4;

    hipMemsetAsync(cnt, 0, NNODES * 4, stream);
    build_wimg<<<72, NTH, 0, stream>>>(We1, We2, We3, Wn1, Wn2, Wn3, img_e, img_n);

    const int egrid = (NEDGES + NTH - 1) / NTH;
    csr_histo<<<egrid, NTH, 0, stream>>>(receivers, cnt);
    csr_scan<<<1, 1024, 0, stream>>>(cnt, off, cursor);
    csr_fill<<<egrid, NTH, 0, stream>>>(receivers, cursor, elist);

    mgn_mfma<0><<<dim3((NEDGES + 127) / 128), dim3(NTH), 0, stream>>>(
        nodef, edgef, senders, receivers, img_e,
        be1, be2, be3, ge, bege, agg, out_edge);

    aggregate<<<(NNODES + 3) / 4, NTH, 0, stream>>>(out_edge, edgef, off, elist, agg);

    mgn_mfma<1><<<dim3((NNODES + 127) / 128), dim3(NTH), 0, stream>>>(
        nodef, edgef, senders, receivers, img_n,
        bn1, bn2, bn3, gn, begn, agg, out_node);
}